// Round 9
// baseline (39.167 us; speedup 1.0000x reference)
//
#include <hip/hip_runtime.h>
#include <stdint.h>

#define NN   4096
#define NE   131072
#define KIN  512
#define NH   8
#define HF   256
#define SLOPE 0.2f
#define MAXD 160

typedef __attribute__((ext_vector_type(8))) short bf16x8;
typedef __attribute__((ext_vector_type(4))) float f32x4;

// ws layout: [0,16KB) cnt | [16KB,+1.25MB) lst u16 | [2MB,4MB) gbf bf16 |
//            [4MB,+128K) el | +128K er | [4.25MB,+256K) Btbf (W_fc^T bf16)

__device__ __forceinline__ unsigned short f2bf(float x) {  // RTN-even f32->bf16
  unsigned u = __builtin_bit_cast(unsigned, x);
  u += 0x7FFFu + ((u >> 16) & 1u);
  return (unsigned short)(u >> 16);
}
__device__ __forceinline__ float bf2f(unsigned short x) {
  unsigned u = ((unsigned)x) << 16;
  return __builtin_bit_cast(float, u);
}
__device__ __forceinline__ unsigned pack2(float lo, float hi) {
  return (unsigned)f2bf(lo) | ((unsigned)f2bf(hi) << 16);
}

// K1: blocks 0..127 W_fc -> B^T bf16 (32x32 tile transpose); 128..143 clear cnt (16KB)
__global__ __launch_bounds__(256) void prep_k(const float* __restrict__ B,
                                              int* __restrict__ cnt,
                                              unsigned short* __restrict__ Btbf) {
  __shared__ float tile[32][33];
  const int b = blockIdx.x, t = threadIdx.x;
  if (b < 128) {
    int k0 = (b >> 3) * 32, n0 = (b & 7) * 32;
    int lr = t >> 3, lc = (t & 7) * 4;
    float4 v = *(const float4*)&B[(size_t)(k0 + lr) * HF + n0 + lc];
    tile[lr][lc] = v.x; tile[lr][lc + 1] = v.y; tile[lr][lc + 2] = v.z; tile[lr][lc + 3] = v.w;
    __syncthreads();
    ushort4 o;
    o.x = f2bf(tile[lc + 0][lr]); o.y = f2bf(tile[lc + 1][lr]);
    o.z = f2bf(tile[lc + 2][lr]); o.w = f2bf(tile[lc + 3][lr]);
    *(ushort4*)&Btbf[(size_t)(n0 + lr) * KIN + k0 + lc] = o;
  } else {
    cnt[(b - 128) * 256 + t] = 0;
  }
}

// K2: blocks 0..1023 = 32x32 MFMA GEMM tiles (128 M x 8 heads), BK=64 (R7-proven),
//     dbuf LDS, A reg-staged from h (f32->bf16 in-kernel, swizzled ds_write),
//     B via global_load_lds (pre-swizzled source, rule #21); fused el/er epilogue.
//     Blocks 1024..1551 = edge scatter into capped CSR.
__global__ __launch_bounds__(256) void gemm_adj_k(const float* __restrict__ h,
                                                  const unsigned short* __restrict__ Bt,
                                                  const float* __restrict__ Wa,
                                                  unsigned short* __restrict__ gbf,
                                                  float* __restrict__ el,
                                                  float* __restrict__ er,
                                                  const int* __restrict__ ei,
                                                  const float* __restrict__ mask,
                                                  int* __restrict__ cnt,
                                                  unsigned short* __restrict__ lst) {
  __shared__ unsigned short smem[2][4096];  // per buf: A[32][64]@0, B[32][64]@2048
  const int bx = blockIdx.x, t = threadIdx.x;
  if (bx >= 1024) {  // ---- scatter: NE+NN = 135168 = 528*256 exactly ----
    int k = (bx - 1024) * 256 + t;
    int s, d; float m;
    if (k < NE) { s = ei[k]; d = ei[NE + k]; m = mask[k]; }
    else        { s = k - NE; d = s; m = 1.0f; }   // diagonal forced to 1
    if (m != 0.0f) {
      int pos = atomicAdd(&cnt[s], 1);
      if (pos < MAXD) lst[(size_t)s * MAXD + pos] = (unsigned short)d;
    }
    return;
  }
  // ---- gemm: 32x32 tile, gy selects the head (R7 code, verbatim) ----
  const int gx = bx & 127, gy = bx >> 7;
  const int row0 = gx * 32, col0 = gy * 32;
  const int w = t >> 6, l = t & 63;
  const int wr = w >> 1, wc = w & 1;

  const int srow = (w << 3) + (l >> 3);      // wave w stages rows 8w..8w+7
  const int sc   = l & 7;                    // linear k-chunk for A (swizzle on ds_write)
  const int aoff = srow * 64 + ((sc ^ (srow & 7)) << 3);   // swizzled LDS slot (ushorts)
  const float* gA = &h[(size_t)(row0 + srow) * KIN + sc * 8];
  const int schB = sc ^ (srow & 7);          // B source pre-swizzled (rule #21)
  const unsigned short* gB = &Bt[(size_t)(col0 + srow) * KIN + schB * 8];

#define BSTAGE(bf, ks)                                                                            \
  __builtin_amdgcn_global_load_lds(                                                               \
      (const __attribute__((address_space(1))) unsigned int*)(gB + (size_t)(ks) * 64),            \
      (__attribute__((address_space(3))) unsigned int*)(&smem[bf][2048 + w * 512]), 16, 0, 0)

  f32x4 acc = {};
  {
    float4 va0 = *(const float4*)(gA);
    float4 va1 = *(const float4*)(gA + 4);
    BSTAGE(0, 0);
    uint4 w4 = {pack2(va0.x, va0.y), pack2(va0.z, va0.w),
                pack2(va1.x, va1.y), pack2(va1.z, va1.w)};
    *(uint4*)&smem[0][aoff] = w4;
  }
  __syncthreads();

  const int lrow = l & 15, kg = l >> 4;
  const int ar = wr * 16 + lrow, br = wc * 16 + lrow;
  for (int ks = 0; ks < 8; ++ks) {
    const int bf = ks & 1;
    float4 na0, na1;
    if (ks < 7) {                            // issue next-step A loads early (T14)
      na0 = *(const float4*)(gA + (ks + 1) * 64);
      na1 = *(const float4*)(gA + (ks + 1) * 64 + 4);
      BSTAGE(bf ^ 1, ks + 1);
    }
    bf16x8 a0 = *(const bf16x8*)&smem[bf][ar * 64 + ((kg ^ (ar & 7)) << 3)];
    bf16x8 a1 = *(const bf16x8*)&smem[bf][ar * 64 + (((4 + kg) ^ (ar & 7)) << 3)];
    bf16x8 b0 = *(const bf16x8*)&smem[bf][2048 + br * 64 + ((kg ^ (br & 7)) << 3)];
    bf16x8 b1 = *(const bf16x8*)&smem[bf][2048 + br * 64 + (((4 + kg) ^ (br & 7)) << 3)];
    acc = __builtin_amdgcn_mfma_f32_16x16x32_bf16(a0, b0, acc, 0, 0, 0);
    acc = __builtin_amdgcn_mfma_f32_16x16x32_bf16(a1, b1, acc, 0, 0, 0);
    if (ks < 7) {                            // write-late into the other buffer
      uint4 w4 = {pack2(na0.x, na0.y), pack2(na0.z, na0.w),
                  pack2(na1.x, na1.y), pack2(na1.z, na1.w)};
      *(uint4*)&smem[bf ^ 1][aoff] = w4;
    }
    __syncthreads();
  }
#undef BSTAGE

  // C/D: col=lane&15, row=(lane>>4)*4+q  [m89-verified]
  const int crow = (l >> 4) * 4, ccol = l & 15;
  const int gr0 = row0 + wr * 16 + crow, gc = col0 + wc * 16 + ccol;
#pragma unroll
  for (int q = 0; q < 4; ++q) gbf[(size_t)(gr0 + q) * HF + gc] = f2bf(acc[q]);

  // fused el/er: this block's 32 cols == head gy's full f range
  float* red = (float*)smem;                 // reuse after final K-loop sync
  const int f = wc * 16 + ccol;
  const float wal = Wa[f], war = Wa[32 + f];
#pragma unroll
  for (int q = 0; q < 4; ++q) {
    float pel = acc[q] * wal, per = acc[q] * war;
#pragma unroll
    for (int m = 8; m >= 1; m >>= 1) { pel += __shfl_xor(pel, m); per += __shfl_xor(per, m); }
    if (ccol == 0) {
      int rl = wr * 16 + crow + q;
      red[wc * 32 + rl] = pel;
      red[64 + wc * 32 + rl] = per;
    }
  }
  __syncthreads();
  if (t < 32) {
    el[(row0 + t) * NH + gy] = red[t] + red[32 + t];
    er[(row0 + t) * NH + gy] = red[64 + t] + red[96 + t];
  }
}

// K3: one WAVE per row (4 rows/block). Wave dedups its row's capped CSR list in
// a 512B LDS bitmap; __syncthreads() between populate and extract guarantees all
// DS atomics completed (barrier drains lgkmcnt) before read-back -> deterministic
// ascending-j-per-lane-word order regardless of atomicAdd arrival order.
// Lane l owns output elems [l*4, l*4+4) (head l>>3). No max-subtraction:
// |e| small -> exp f32-safe; softmax shift-invariant.
__global__ __launch_bounds__(256) void attn_k(const int* __restrict__ cnt,
                                              const unsigned short* __restrict__ lst,
                                              const unsigned short* __restrict__ gbf,
                                              const float* __restrict__ el_,
                                              const float* __restrict__ er_,
                                              float* __restrict__ out) {
  __shared__ unsigned bm[4][128];            // 2KB: per-wave row bitmap
  __shared__ unsigned short J[4][MAXD];      // 1.25KB
  const int t = threadIdx.x, wv = t >> 6, l = t & 63;
  const int i = blockIdx.x * 4 + wv;

  int n = cnt[i];
  if (n > MAXD) n = MAXD;                    // cap (never hit for this E/N)
  bm[wv][l] = 0; bm[wv][64 + l] = 0;
  __syncthreads();                           // clears visible before atomics
  for (int k = l; k < n; k += 64) {
    int j = lst[(size_t)i * MAXD + k];
    atomicOr(&bm[wv][j >> 5], 1u << (j & 31));
  }
  __syncthreads();                           // all DS atomics complete before read-back
  unsigned w0 = bm[wv][l];
  unsigned w1 = bm[wv][64 + l];
  int c = __popc(w0) + __popc(w1);
  int incl = c;
#pragma unroll
  for (int d = 1; d < 64; d <<= 1) {
    int u = __shfl_up(incl, d);
    if (l >= d) incl += u;
  }
  const int total = __shfl(incl, 63);
  int off = incl - c;
  unsigned short* Jw = J[wv];
  while (w0) { int b = __ffs(w0) - 1; Jw[off++] = (unsigned short)(l * 32 + b); w0 &= w0 - 1; }
  while (w1) { int b = __ffs(w1) - 1; Jw[off++] = (unsigned short)((64 + l) * 32 + b); w1 &= w1 - 1; }
  __syncthreads();

  const int hh = l >> 3;
  const float elh = el_[i * NH + hh];
  const unsigned short* gp = gbf + (size_t)l * 4;
  f32x4 acc = {};
  float den = 0.f;
#pragma unroll 2
  for (int k = 0; k < total; ++k) {
    int j = Jw[k];                           // LDS broadcast
    float e  = elh + er_[j * NH + hh];
    float lr = e > 0.f ? e : SLOPE * e;
    float wg = __expf(lr);
    ushort4 gv = *(const ushort4*)(gp + (size_t)j * HF);
    den += wg;
    acc[0] += wg * bf2f(gv.x);
    acc[1] += wg * bf2f(gv.y);
    acc[2] += wg * bf2f(gv.z);
    acc[3] += wg * bf2f(gv.w);
  }
  float inv = 1.f / den;
  float4 o = make_float4(acc[0] * inv, acc[1] * inv, acc[2] * inv, acc[3] * inv);
  *(float4*)&out[(size_t)i * HF + l * 4] = o;
}

extern "C" void kernel_launch(void* const* d_in, const int* in_sizes, int n_in,
                              void* d_out, int out_size, void* d_ws, size_t ws_size,
                              hipStream_t stream) {
  const float* h      = (const float*)d_in[0];
  const int*   ei     = (const int*)d_in[1];
  const float* mask   = (const float*)d_in[2];
  const float* W_fc   = (const float*)d_in[3];
  const float* W_attn = (const float*)d_in[4];
  float* out = (float*)d_out;

  char* ws = (char*)d_ws;
  int* cnt              = (int*)ws;                                               // 16 KB
  unsigned short* lst   = (unsigned short*)(ws + 16 * 1024);                      // 1.25 MB
  unsigned short* gbf   = (unsigned short*)(ws + (size_t)2 * 1024 * 1024);        // 2 MB
  float* el             = (float*)(ws + (size_t)4 * 1024 * 1024);                 // 128 KB
  float* er             = (float*)(ws + (size_t)4 * 1024 * 1024 + 128 * 1024);    // 128 KB
  unsigned short* Btbf  = (unsigned short*)(ws + (size_t)4 * 1024 * 1024 + 256 * 1024);  // 256 KB

  prep_k<<<144, 256, 0, stream>>>(W_fc, cnt, Btbf);
  gemm_adj_k<<<1024 + 528, 256, 0, stream>>>(h, Btbf, W_attn, gbf, el, er, ei, mask, cnt, lst);
  attn_k<<<NN / 4, 256, 0, stream>>>(cnt, lst, gbf, el, er, out);
}

// Round 10
// 33.752 us; speedup vs baseline: 1.1604x; 1.1604x over previous
//
#include <hip/hip_runtime.h>
#include <stdint.h>

#define NN   4096
#define NE   131072
#define KIN  512
#define NH   8
#define HF   256
#define SLOPE 0.2f
#define MAXJ 256

typedef __attribute__((ext_vector_type(8))) short bf16x8;
typedef __attribute__((ext_vector_type(4))) float f32x4;

// ws layout: [0,2MB) bitmap | [2,4MB) gbf bf16 | [4MB,+128K) el | +128K er |
//            [4.25MB,+256K) Btbf (W_fc^T bf16)

__device__ __forceinline__ unsigned short f2bf(float x) {  // RTN-even f32->bf16
  unsigned u = __builtin_bit_cast(unsigned, x);
  u += 0x7FFFu + ((u >> 16) & 1u);
  return (unsigned short)(u >> 16);
}
__device__ __forceinline__ float bf2f(unsigned short x) {
  unsigned u = ((unsigned)x) << 16;
  return __builtin_bit_cast(float, u);
}
__device__ __forceinline__ unsigned pack2(float lo, float hi) {
  return (unsigned)f2bf(lo) | ((unsigned)f2bf(hi) << 16);
}

// K1: blocks 0..511 clear bitmap; 512..639 W_fc -> B^T bf16 (32x32 tile transpose)
__global__ __launch_bounds__(256) void prep_k(const float* __restrict__ B,
                                              unsigned* __restrict__ bitmap,
                                              unsigned short* __restrict__ Btbf) {
  __shared__ float tile[32][33];
  const int b = blockIdx.x, t = threadIdx.x;
  if (b < 512) {
    ((float4*)bitmap)[b * 256 + t] = make_float4(0.f, 0.f, 0.f, 0.f);
  } else {
    int bb = b - 512;
    int k0 = (bb >> 3) * 32, n0 = (bb & 7) * 32;
    int lr = t >> 3, lc = (t & 7) * 4;
    float4 v = *(const float4*)&B[(size_t)(k0 + lr) * HF + n0 + lc];
    tile[lr][lc] = v.x; tile[lr][lc + 1] = v.y; tile[lr][lc + 2] = v.z; tile[lr][lc + 3] = v.w;
    __syncthreads();
    ushort4 o;
    o.x = f2bf(tile[lc + 0][lr]); o.y = f2bf(tile[lc + 1][lr]);
    o.z = f2bf(tile[lc + 2][lr]); o.w = f2bf(tile[lc + 3][lr]);
    *(ushort4*)&Btbf[(size_t)(n0 + lr) * KIN + k0 + lc] = o;
  }
}

// K2: blocks 0..1023 = 32x32 MFMA GEMM tiles (128 M x 8 heads), BK=64, dbuf,
//     A reg-staged straight from h (f32->bf16 in-kernel), B via global_load_lds;
//     fused el/er epilogue. Blocks 1024..1551 = build_adj (bitmap atomicOr).
__global__ __launch_bounds__(256) void gemm_adj_k(const float* __restrict__ h,
                                                  const unsigned short* __restrict__ Bt,
                                                  const float* __restrict__ Wa,
                                                  unsigned short* __restrict__ gbf,
                                                  float* __restrict__ el,
                                                  float* __restrict__ er,
                                                  const int* __restrict__ ei,
                                                  const float* __restrict__ mask,
                                                  unsigned* __restrict__ bitmap) {
  __shared__ unsigned short smem[2][4096];  // per buf: A[32][64]@0, B[32][64]@2048
  const int bx = blockIdx.x, t = threadIdx.x;
  if (bx >= 1024) {  // ---- build_adj: NE+NN = 135168 = 528*256 exactly ----
    int k = (bx - 1024) * 256 + t;
    int s, d; float m;
    if (k < NE) { s = ei[k]; d = ei[NE + k]; m = mask[k]; }
    else        { s = k - NE; d = s; m = 1.0f; }   // diagonal forced to 1
    if (m != 0.0f) atomicOr(&bitmap[s * 128 + (d >> 5)], 1u << (d & 31));
    return;
  }
  // ---- gemm: 32x32 tile, gy selects the head ----
  const int gx = bx & 127, gy = bx >> 7;
  const int row0 = gx * 32, col0 = gy * 32;
  const int w = t >> 6, l = t & 63;
  const int wr = w >> 1, wc = w & 1;

  const int srow = (w << 3) + (l >> 3);      // wave w stages rows 8w..8w+7
  const int sc   = l & 7;                    // linear k-chunk for A (swizzle on ds_write)
  const int aoff = srow * 64 + ((sc ^ (srow & 7)) << 3);   // swizzled LDS slot (ushorts)
  const float* gA = &h[(size_t)(row0 + srow) * KIN + sc * 8];
  const int schB = sc ^ (srow & 7);          // B source pre-swizzled (rule #21)
  const unsigned short* gB = &Bt[(size_t)(col0 + srow) * KIN + schB * 8];

#define BSTAGE(bf, ks)                                                                            \
  __builtin_amdgcn_global_load_lds(                                                               \
      (const __attribute__((address_space(1))) unsigned int*)(gB + (size_t)(ks) * 64),            \
      (__attribute__((address_space(3))) unsigned int*)(&smem[bf][2048 + w * 512]), 16, 0, 0)

  f32x4 acc = {};
  {
    float4 va0 = *(const float4*)(gA);
    float4 va1 = *(const float4*)(gA + 4);
    BSTAGE(0, 0);
    uint4 w4 = {pack2(va0.x, va0.y), pack2(va0.z, va0.w),
                pack2(va1.x, va1.y), pack2(va1.z, va1.w)};
    *(uint4*)&smem[0][aoff] = w4;
  }
  __syncthreads();

  const int lrow = l & 15, kg = l >> 4;
  const int ar = wr * 16 + lrow, br = wc * 16 + lrow;
  for (int ks = 0; ks < 8; ++ks) {
    const int bf = ks & 1;
    float4 na0, na1;
    if (ks < 7) {                            // issue next-step A loads early (T14)
      na0 = *(const float4*)(gA + (ks + 1) * 64);
      na1 = *(const float4*)(gA + (ks + 1) * 64 + 4);
      BSTAGE(bf ^ 1, ks + 1);
    }
    bf16x8 a0 = *(const bf16x8*)&smem[bf][ar * 64 + ((kg ^ (ar & 7)) << 3)];
    bf16x8 a1 = *(const bf16x8*)&smem[bf][ar * 64 + (((4 + kg) ^ (ar & 7)) << 3)];
    bf16x8 b0 = *(const bf16x8*)&smem[bf][2048 + br * 64 + ((kg ^ (br & 7)) << 3)];
    bf16x8 b1 = *(const bf16x8*)&smem[bf][2048 + br * 64 + (((4 + kg) ^ (br & 7)) << 3)];
    acc = __builtin_amdgcn_mfma_f32_16x16x32_bf16(a0, b0, acc, 0, 0, 0);
    acc = __builtin_amdgcn_mfma_f32_16x16x32_bf16(a1, b1, acc, 0, 0, 0);
    if (ks < 7) {                            // write-late into the other buffer
      uint4 w4 = {pack2(na0.x, na0.y), pack2(na0.z, na0.w),
                  pack2(na1.x, na1.y), pack2(na1.z, na1.w)};
      *(uint4*)&smem[bf ^ 1][aoff] = w4;
    }
    __syncthreads();
  }
#undef BSTAGE

  // C/D: col=lane&15, row=(lane>>4)*4+q  [m89-verified]
  const int crow = (l >> 4) * 4, ccol = l & 15;
  const int gr0 = row0 + wr * 16 + crow, gc = col0 + wc * 16 + ccol;
#pragma unroll
  for (int q = 0; q < 4; ++q) gbf[(size_t)(gr0 + q) * HF + gc] = f2bf(acc[q]);

  // fused el/er: this block's 32 cols == head gy's full f range
  float* red = (float*)smem;                 // reuse after final K-loop sync
  const int f = wc * 16 + ccol;
  const float wal = Wa[f], war = Wa[32 + f];
#pragma unroll
  for (int q = 0; q < 4; ++q) {
    float pel = acc[q] * wal, per = acc[q] * war;
#pragma unroll
    for (int m = 8; m >= 1; m >>= 1) { pel += __shfl_xor(pel, m); per += __shfl_xor(per, m); }
    if (ccol == 0) {
      int rl = wr * 16 + crow + q;
      red[wc * 32 + rl] = pel;
      red[64 + wc * 32 + rl] = per;
    }
  }
  __syncthreads();
  if (t < 32) {
    el[(row0 + t) * NH + gy] = red[t] + red[32 + t];
    er[(row0 + t) * NH + gy] = red[64 + t] + red[96 + t];
  }
}

// K3: one WAVE per row (4 rows/block). Lane l owns output elems [l*4, l*4+4)
// (head l>>3). Wave-local bitmap expand; 4-way MLP gather loop with two
// independent accumulator pairs. No max-subtraction: |e| small -> exp f32-safe.
__global__ __launch_bounds__(256) void attn_k(const unsigned* __restrict__ bitmap,
                                              const unsigned short* __restrict__ gbf,
                                              const float* __restrict__ el_,
                                              const float* __restrict__ er_,
                                              float* __restrict__ out) {
  __shared__ unsigned short jl[4][MAXJ];     // 2KB (max degree ~65; 256 = huge margin)
  const int t = threadIdx.x, wv = t >> 6, l = t & 63;
  const int i = blockIdx.x * 4 + wv;

  unsigned w0 = bitmap[i * 128 + l];
  unsigned w1 = bitmap[i * 128 + 64 + l];
  int cnt = __popc(w0) + __popc(w1);
  int incl = cnt;
#pragma unroll
  for (int d = 1; d < 64; d <<= 1) {
    int u = __shfl_up(incl, d);
    if (l >= d) incl += u;
  }
  int total = __shfl(incl, 63);
  if (total > MAXJ) total = MAXJ;
  int off = incl - cnt;
  unsigned short* J = jl[wv];
  while (w0) {
    int b = __ffs(w0) - 1;
    if (off < MAXJ) J[off] = (unsigned short)(l * 32 + b);
    ++off; w0 &= w0 - 1;
  }
  while (w1) {
    int b = __ffs(w1) - 1;
    if (off < MAXJ) J[off] = (unsigned short)((64 + l) * 32 + b);
    ++off; w1 &= w1 - 1;
  }
  __syncthreads();

  const int hh = l >> 3;
  const float elh = el_[i * NH + hh];
  const unsigned short* gp = gbf + (size_t)l * 4;
  f32x4 accA = {}, accB = {};
  float den0 = 0.f, den1 = 0.f;
  int k = 0;
  for (; k + 4 <= total; k += 4) {           // 4-way MLP: 4 rows + 4 er in flight
    int j0 = J[k], j1 = J[k + 1], j2 = J[k + 2], j3 = J[k + 3];
    float e0 = elh + er_[j0 * NH + hh];
    float e1 = elh + er_[j1 * NH + hh];
    float e2 = elh + er_[j2 * NH + hh];
    float e3 = elh + er_[j3 * NH + hh];
    ushort4 g0 = *(const ushort4*)(gp + (size_t)j0 * HF);
    ushort4 g1 = *(const ushort4*)(gp + (size_t)j1 * HF);
    ushort4 g2 = *(const ushort4*)(gp + (size_t)j2 * HF);
    ushort4 g3 = *(const ushort4*)(gp + (size_t)j3 * HF);
    float l0 = e0 > 0.f ? e0 : SLOPE * e0;
    float l1 = e1 > 0.f ? e1 : SLOPE * e1;
    float l2 = e2 > 0.f ? e2 : SLOPE * e2;
    float l3 = e3 > 0.f ? e3 : SLOPE * e3;
    float wg0 = __expf(l0), wg1 = __expf(l1), wg2 = __expf(l2), wg3 = __expf(l3);
    den0 += wg0 + wg2; den1 += wg1 + wg3;
    accA[0] += wg0 * bf2f(g0.x); accB[0] += wg1 * bf2f(g1.x);
    accA[1] += wg0 * bf2f(g0.y); accB[1] += wg1 * bf2f(g1.y);
    accA[2] += wg0 * bf2f(g0.z); accB[2] += wg1 * bf2f(g1.z);
    accA[3] += wg0 * bf2f(g0.w); accB[3] += wg1 * bf2f(g1.w);
    accA[0] += wg2 * bf2f(g2.x); accB[0] += wg3 * bf2f(g3.x);
    accA[1] += wg2 * bf2f(g2.y); accB[1] += wg3 * bf2f(g3.y);
    accA[2] += wg2 * bf2f(g2.z); accB[2] += wg3 * bf2f(g3.z);
    accA[3] += wg2 * bf2f(g2.w); accB[3] += wg3 * bf2f(g3.w);
  }
  for (; k < total; ++k) {
    int j0 = J[k];
    float e0 = elh + er_[j0 * NH + hh];
    float l0 = e0 > 0.f ? e0 : SLOPE * e0;
    float wg0 = __expf(l0);
    ushort4 g0 = *(const ushort4*)(gp + (size_t)j0 * HF);
    den0 += wg0;
    accA[0] += wg0 * bf2f(g0.x); accA[1] += wg0 * bf2f(g0.y);
    accA[2] += wg0 * bf2f(g0.z); accA[3] += wg0 * bf2f(g0.w);
  }
  float inv = 1.f / (den0 + den1);
  float4 o = make_float4((accA[0] + accB[0]) * inv, (accA[1] + accB[1]) * inv,
                         (accA[2] + accB[2]) * inv, (accA[3] + accB[3]) * inv);
  *(float4*)&out[(size_t)i * HF + l * 4] = o;
}

extern "C" void kernel_launch(void* const* d_in, const int* in_sizes, int n_in,
                              void* d_out, int out_size, void* d_ws, size_t ws_size,
                              hipStream_t stream) {
  const float* h      = (const float*)d_in[0];
  const int*   ei     = (const int*)d_in[1];
  const float* mask   = (const float*)d_in[2];
  const float* W_fc   = (const float*)d_in[3];
  const float* W_attn = (const float*)d_in[4];
  float* out = (float*)d_out;

  char* ws = (char*)d_ws;
  unsigned* bitmap      = (unsigned*)ws;                                          // 2 MB
  unsigned short* gbf   = (unsigned short*)(ws + (size_t)2 * 1024 * 1024);        // 2 MB
  float* el             = (float*)(ws + (size_t)4 * 1024 * 1024);                 // 128 KB
  float* er             = (float*)(ws + (size_t)4 * 1024 * 1024 + 128 * 1024);    // 128 KB
  unsigned short* Btbf  = (unsigned short*)(ws + (size_t)4 * 1024 * 1024 + 256 * 1024);  // 256 KB

  prep_k<<<640, 256, 0, stream>>>(W_fc, bitmap, Btbf);
  gemm_adj_k<<<1024 + 528, 256, 0, stream>>>(h, Btbf, W_attn, gbf, el, er, ei, mask, bitmap);
  attn_k<<<NN / 4, 256, 0, stream>>>(bitmap, gbf, el, er, out);
}